// Round 8
// baseline (92.894 us; speedup 1.0000x reference)
//
#include <hip/hip_runtime.h>
#include <math.h>

#define N 1024
#define H 128
#define CLIPV 10.0f

#define TI 64
#define TJ 64
#define LDSP 132           // padded row stride: 132 % 32 = 4 -> 4-bank rotation/row
#define NBLK ((N / TI) * (N / TJ))   // 256 pair-blocks

// ---------------------------------------------------------------------------
// Kernel A (R3-proven, untouched): A[j][h]  = z_c @ w1[:128]
//                                  Cb[i][h] = z_d @ w1[128:] + b1
// Block (0,0) zeroes acc/counter for k_pair (kernel-boundary visible).
// ---------------------------------------------------------------------------
__global__ __launch_bounds__(256) void k_gemm(const float* __restrict__ z_c,
                                              const float* __restrict__ z_d,
                                              const float* __restrict__ w1,
                                              const float* __restrict__ b1,
                                              float* __restrict__ A,
                                              float* __restrict__ Cb,
                                              double* __restrict__ acc,
                                              int* __restrict__ counter) {
    const int which = blockIdx.y;            // 0 -> A, 1 -> Cb
    const int n0 = blockIdx.x * 8;
    const int tid = threadIdx.x;
    if (blockIdx.x == 0 && which == 0 && tid == 0) {
        acc[0] = 0.0; acc[1] = 0.0; *counter = 0;
    }
    const float* __restrict__ z = which ? z_d : z_c;
    const float* __restrict__ w = w1 + which * (H * H);

    __shared__ float zs[8][H];
    {
        const int c4 = (tid & 31) * 4;
        const int r  = tid >> 5;             // 0..7
        *(float4*)&zs[r][c4] = *(const float4*)&z[(n0 + r) * H + c4];
    }
    __syncthreads();

    const int h = tid & 127;
    const int g = tid >> 7;                  // row-group 0/1 (rows g*4..g*4+3)

    float a0 = 0.f, a1 = 0.f, a2 = 0.f, a3 = 0.f;
    #pragma unroll 8
    for (int k = 0; k < H; ++k) {
        const float wv = w[k * H + h];
        a0 = fmaf(zs[g * 4 + 0][k], wv, a0);
        a1 = fmaf(zs[g * 4 + 1][k], wv, a1);
        a2 = fmaf(zs[g * 4 + 2][k], wv, a2);
        a3 = fmaf(zs[g * 4 + 3][k], wv, a3);
    }
    const float bias = which ? b1[h] : 0.0f;
    float* __restrict__ dst = which ? Cb : A;
    dst[(n0 + g * 4 + 0) * H + h] = a0 + bias;
    dst[(n0 + g * 4 + 1) * H + h] = a1 + bias;
    dst[(n0 + g * 4 + 2) * H + h] = a2 + bias;
    dst[(n0 + g * 4 + 3) * H + h] = a3 + bias;
}

// ---------------------------------------------------------------------------
// Kernel B: 64x64 tile, 512 threads = 2 h-halves x 256 compute threads.
// Delta vs R5: inner loop restructured to fit the 128-VGPR cap without
// spills — unroll 2 (not 4), af consumed immediately per dj instead of
// holding af[4] alongside cf[4]. Live set ~100 VGPR.
// (512,4) -> 16 waves/CU = 2 blocks/CU (LDS 68KB*2 = 136 <= 160KB).
// ---------------------------------------------------------------------------
__global__ __launch_bounds__(512, 4) void k_pair(const float* __restrict__ A,
                                                 const float* __restrict__ Cb,
                                                 const float* __restrict__ w2,
                                                 const float* __restrict__ b2p,
                                                 double* __restrict__ acc,
                                                 int* __restrict__ counter,
                                                 float* __restrict__ out) {
    __shared__ float Ash[TJ][LDSP];
    __shared__ float Csh[TI][LDSP];
    __shared__ float w2s[H];
    __shared__ float red[16];

    const int tid = threadIdx.x;
    const int i0 = blockIdx.x * TI;
    const int j0 = blockIdx.y * TJ;

    // ---- staging: 512 threads, 128 rows (64 A + 64 C) x 32 float4 cols ----
    {
        const int c4 = (tid & 31) * 4;
        const int r  = tid >> 5;             // 0..15
        #pragma unroll
        for (int rr = 0; rr < 4; ++rr) {
            const int row = r + rr * 16;     // 0..63
            *(float4*)&Ash[row][c4] = *(const float4*)&A[(j0 + row) * H + c4];
            *(float4*)&Csh[row][c4] = *(const float4*)&Cb[(i0 + row) * H + c4];
        }
        if (tid < 32) *(float4*)&w2s[tid * 4] = *(const float4*)&w2[tid * 4];
    }
    __syncthreads();

    const int t256 = tid & 255;
    const int tj = t256 & 15;                // j group (16)
    const int ti = t256 >> 4;                // i group (16)
    const int hh = tid >> 8;                 // h-half 0/1

    float s[4][4] = {{0.f,0.f,0.f,0.f},{0.f,0.f,0.f,0.f},
                     {0.f,0.f,0.f,0.f},{0.f,0.f,0.f,0.f}};

    const int h4base = hh * 16;
    #pragma unroll 2
    for (int h4i = 0; h4i < 16; ++h4i) {
        const int h4 = h4base + h4i;
        const float4 w4 = *(const float4*)&w2s[h4 * 4];
        float4 cf[4];
        #pragma unroll
        for (int d = 0; d < 4; ++d)
            cf[d] = *(const float4*)&Csh[ti + d * 16][h4 * 4];
        #pragma unroll
        for (int dj = 0; dj < 4; ++dj) {
            const float4 af = *(const float4*)&Ash[tj + dj * 16][h4 * 4];
            #pragma unroll
            for (int q = 0; q < 4; ++q) {
                const float wv = ((const float*)&w4)[q];
                const float av = ((const float*)&af)[q];
                #pragma unroll
                for (int di = 0; di < 4; ++di) {
                    const float t = fmaxf(((const float*)&cf[di])[q] + av, 0.f);
                    s[di][dj] = fmaf(t, wv, s[di][dj]);
                }
            }
        }
    }

    // ---- combine h-halves (reuse Ash as scratch; stride 20 -> <=2-way) ----
    float* comb = &Ash[0][0];                // 256*20 = 5120 <= 64*132
    __syncthreads();
    if (hh == 1) {
        #pragma unroll
        for (int di = 0; di < 4; ++di) {
            float4 v4;
            v4.x = s[di][0]; v4.y = s[di][1]; v4.z = s[di][2]; v4.w = s[di][3];
            *(float4*)&comb[t256 * 20 + di * 4] = v4;
        }
    }
    __syncthreads();

    float diag = 0.f, sume = 0.f;
    if (hh == 0) {
        const float b2 = b2p[0];
        #pragma unroll
        for (int di = 0; di < 4; ++di) {
            #pragma unroll
            for (int dj = 0; dj < 4; ++dj) {
                const float v = s[di][dj] + comb[t256 * 20 + di * 4 + dj] + b2;
                const int i = i0 + ti + di * 16;
                const int j = j0 + tj + dj * 16;
                if (i == j) {
                    diag += v;
                } else {
                    const float vc = fminf(fmaxf(v, -CLIPV), CLIPV);
                    sume += __expf(vc - CLIPV);
                }
            }
        }
    }

    // ---- block reduction: wave shuffle, LDS across 8 waves, atomics ----
    #pragma unroll
    for (int off = 32; off; off >>= 1) {
        diag += __shfl_down(diag, off);
        sume += __shfl_down(sume, off);
    }
    if ((tid & 63) == 0) { red[tid >> 6] = diag; red[8 + (tid >> 6)] = sume; }
    __syncthreads();
    if (tid == 0) {
        float d = 0.f, e = 0.f;
        #pragma unroll
        for (int k = 0; k < 8; ++k) { d += red[k]; e += red[8 + k]; }
        atomicAdd(&acc[0], (double)d);
        atomicAdd(&acc[1], (double)e);
        __threadfence();
        const int old = atomicAdd(counter, 1);
        if (old == NBLK - 1) {               // last block finalizes
            const double dt = atomicAdd(&acc[0], 0.0);   // coherent read
            const double et = atomicAdd(&acc[1], 0.0);
            const double T0  = dt / (double)N;
            const double lme = log(et) + (double)CLIPV
                             - log((double)N * ((double)N - 1.0));
            out[0] = (float)(T0 - lme);
        }
    }
}

extern "C" void kernel_launch(void* const* d_in, const int* in_sizes, int n_in,
                              void* d_out, int out_size, void* d_ws, size_t ws_size,
                              hipStream_t stream) {
    const float* z_c = (const float*)d_in[0];
    const float* z_d = (const float*)d_in[1];
    const float* w1  = (const float*)d_in[2];
    const float* b1  = (const float*)d_in[3];
    const float* w2  = (const float*)d_in[4];
    const float* b2  = (const float*)d_in[5];

    float*  A       = (float*)d_ws;                    // N*H
    float*  Cb      = A + N * H;                       // N*H
    double* acc     = (double*)(Cb + N * H);           // 2 doubles
    int*    counter = (int*)(acc + 2);

    k_gemm<<<dim3(N / 8, 2), 256, 0, stream>>>(z_c, z_d, w1, b1, A, Cb,
                                               acc, counter);
    k_pair<<<dim3(N / TI, N / TJ), 512, 0, stream>>>(A, Cb, w2, b2,
                                                     acc, counter,
                                                     (float*)d_out);
}

// Round 9
// 91.679 us; speedup vs baseline: 1.0133x; 1.0133x over previous
//
#include <hip/hip_runtime.h>
#include <math.h>

#define N 1024
#define H 128
#define CLIPV 10.0f

#define TI 64
#define TJ 64
#define LDSP 132           // padded row stride: 132 % 32 = 4 -> 4-bank rotation/row
#define NBLK ((N / TI) * (N / TJ))   // 256 pair-blocks

// ---------------------------------------------------------------------------
// Kernel A (R3-proven): A[j][h]  = z_c @ w1[:128]
//                       Cb[i][h] = z_d @ w1[128:] + b1
// Block (0,0) zeroes acc/counter for k_pair (kernel-boundary visible).
// ---------------------------------------------------------------------------
__global__ __launch_bounds__(256) void k_gemm(const float* __restrict__ z_c,
                                              const float* __restrict__ z_d,
                                              const float* __restrict__ w1,
                                              const float* __restrict__ b1,
                                              float* __restrict__ A,
                                              float* __restrict__ Cb,
                                              double* __restrict__ acc,
                                              int* __restrict__ counter) {
    const int which = blockIdx.y;            // 0 -> A, 1 -> Cb
    const int n0 = blockIdx.x * 8;
    const int tid = threadIdx.x;
    if (blockIdx.x == 0 && which == 0 && tid == 0) {
        acc[0] = 0.0; acc[1] = 0.0; *counter = 0;
    }
    const float* __restrict__ z = which ? z_d : z_c;
    const float* __restrict__ w = w1 + which * (H * H);

    __shared__ float zs[8][H];
    {
        const int c4 = (tid & 31) * 4;
        const int r  = tid >> 5;             // 0..7
        *(float4*)&zs[r][c4] = *(const float4*)&z[(n0 + r) * H + c4];
    }
    __syncthreads();

    const int h = tid & 127;
    const int g = tid >> 7;                  // row-group 0/1 (rows g*4..g*4+3)

    float a0 = 0.f, a1 = 0.f, a2 = 0.f, a3 = 0.f;
    #pragma unroll 8
    for (int k = 0; k < H; ++k) {
        const float wv = w[k * H + h];
        a0 = fmaf(zs[g * 4 + 0][k], wv, a0);
        a1 = fmaf(zs[g * 4 + 1][k], wv, a1);
        a2 = fmaf(zs[g * 4 + 2][k], wv, a2);
        a3 = fmaf(zs[g * 4 + 3][k], wv, a3);
    }
    const float bias = which ? b1[h] : 0.0f;
    float* __restrict__ dst = which ? Cb : A;
    dst[(n0 + g * 4 + 0) * H + h] = a0 + bias;
    dst[(n0 + g * 4 + 1) * H + h] = a1 + bias;
    dst[(n0 + g * 4 + 2) * H + h] = a2 + bias;
    dst[(n0 + g * 4 + 3) * H + h] = a3 + bias;
}

// ---------------------------------------------------------------------------
// Kernel B: EXACT R3 body ((512,1), unroll 4, af[4]+cf[4] held — the 82.8 µs
// proven config; the (512,4) VGPR cap was a -11% regression, R5/R8).
// Only delta vs R3: tail writes per-block partials via two f64 atomics +
// device counter; last block finalizes (removes the k_final dispatch).
// ---------------------------------------------------------------------------
__global__ __launch_bounds__(512, 1) void k_pair(const float* __restrict__ A,
                                                 const float* __restrict__ Cb,
                                                 const float* __restrict__ w2,
                                                 const float* __restrict__ b2p,
                                                 double* __restrict__ acc,
                                                 int* __restrict__ counter,
                                                 float* __restrict__ out) {
    __shared__ float Ash[TJ][LDSP];
    __shared__ float Csh[TI][LDSP];
    __shared__ float w2s[H];
    __shared__ float red[16];

    const int tid = threadIdx.x;
    const int i0 = blockIdx.x * TI;
    const int j0 = blockIdx.y * TJ;

    // ---- staging: 512 threads, 128 rows (64 A + 64 C) x 32 float4 cols ----
    {
        const int c4 = (tid & 31) * 4;
        const int r  = tid >> 5;             // 0..15
        #pragma unroll
        for (int rr = 0; rr < 4; ++rr) {
            const int row = r + rr * 16;     // 0..63
            *(float4*)&Ash[row][c4] = *(const float4*)&A[(j0 + row) * H + c4];
            *(float4*)&Csh[row][c4] = *(const float4*)&Cb[(i0 + row) * H + c4];
        }
        if (tid < 32) *(float4*)&w2s[tid * 4] = *(const float4*)&w2[tid * 4];
    }
    __syncthreads();

    const int t256 = tid & 255;
    const int tj = t256 & 15;                // j group (16)
    const int ti = t256 >> 4;                // i group (16)
    const int hh = tid >> 8;                 // h-half 0/1

    float s[4][4] = {{0.f,0.f,0.f,0.f},{0.f,0.f,0.f,0.f},
                     {0.f,0.f,0.f,0.f},{0.f,0.f,0.f,0.f}};

    const int h4base = hh * 16;
    #pragma unroll 4
    for (int h4i = 0; h4i < 16; ++h4i) {
        const int h4 = h4base + h4i;
        const float4 w4 = *(const float4*)&w2s[h4 * 4];
        float4 cf[4], af[4];
        #pragma unroll
        for (int d = 0; d < 4; ++d) {
            cf[d] = *(const float4*)&Csh[ti + d * 16][h4 * 4];
            af[d] = *(const float4*)&Ash[tj + d * 16][h4 * 4];
        }
        #pragma unroll
        for (int q = 0; q < 4; ++q) {
            const float wv = ((const float*)&w4)[q];
            #pragma unroll
            for (int di = 0; di < 4; ++di) {
                const float cv = ((const float*)&cf[di])[q];
                #pragma unroll
                for (int dj = 0; dj < 4; ++dj) {
                    const float t = fmaxf(cv + ((const float*)&af[dj])[q], 0.f);
                    s[di][dj] = fmaf(t, wv, s[di][dj]);
                }
            }
        }
    }

    // ---- combine h-halves (reuse Ash as scratch; stride 20 -> <=2-way) ----
    float* comb = &Ash[0][0];                // 256*20 = 5120 <= 64*132
    __syncthreads();
    if (hh == 1) {
        #pragma unroll
        for (int di = 0; di < 4; ++di) {
            float4 v4;
            v4.x = s[di][0]; v4.y = s[di][1]; v4.z = s[di][2]; v4.w = s[di][3];
            *(float4*)&comb[t256 * 20 + di * 4] = v4;
        }
    }
    __syncthreads();

    float diag = 0.f, sume = 0.f;
    if (hh == 0) {
        const float b2 = b2p[0];
        #pragma unroll
        for (int di = 0; di < 4; ++di) {
            #pragma unroll
            for (int dj = 0; dj < 4; ++dj) {
                const float v = s[di][dj] + comb[t256 * 20 + di * 4 + dj] + b2;
                const int i = i0 + ti + di * 16;
                const int j = j0 + tj + dj * 16;
                if (i == j) {
                    diag += v;
                } else {
                    const float vc = fminf(fmaxf(v, -CLIPV), CLIPV);
                    sume += __expf(vc - CLIPV);
                }
            }
        }
    }

    // ---- block reduction: wave shuffle, LDS across 8 waves, atomics ----
    #pragma unroll
    for (int off = 32; off; off >>= 1) {
        diag += __shfl_down(diag, off);
        sume += __shfl_down(sume, off);
    }
    if ((tid & 63) == 0) { red[tid >> 6] = diag; red[8 + (tid >> 6)] = sume; }
    __syncthreads();
    if (tid == 0) {
        float d = 0.f, e = 0.f;
        #pragma unroll
        for (int k = 0; k < 8; ++k) { d += red[k]; e += red[8 + k]; }
        atomicAdd(&acc[0], (double)d);
        atomicAdd(&acc[1], (double)e);
        __threadfence();
        const int old = atomicAdd(counter, 1);
        if (old == NBLK - 1) {               // last block finalizes
            const double dt = atomicAdd(&acc[0], 0.0);   // coherent read
            const double et = atomicAdd(&acc[1], 0.0);
            const double T0  = dt / (double)N;
            const double lme = log(et) + (double)CLIPV
                             - log((double)N * ((double)N - 1.0));
            out[0] = (float)(T0 - lme);
        }
    }
}

extern "C" void kernel_launch(void* const* d_in, const int* in_sizes, int n_in,
                              void* d_out, int out_size, void* d_ws, size_t ws_size,
                              hipStream_t stream) {
    const float* z_c = (const float*)d_in[0];
    const float* z_d = (const float*)d_in[1];
    const float* w1  = (const float*)d_in[2];
    const float* b1  = (const float*)d_in[3];
    const float* w2  = (const float*)d_in[4];
    const float* b2  = (const float*)d_in[5];

    float*  A       = (float*)d_ws;                    // N*H
    float*  Cb      = A + N * H;                       // N*H
    double* acc     = (double*)(Cb + N * H);           // 2 doubles
    int*    counter = (int*)(acc + 2);

    k_gemm<<<dim3(N / 8, 2), 256, 0, stream>>>(z_c, z_d, w1, b1, A, Cb,
                                               acc, counter);
    k_pair<<<dim3(N / TI, N / TJ), 512, 0, stream>>>(A, Cb, w2, b2,
                                                     acc, counter,
                                                     (float*)d_out);
}

// Round 10
// 82.660 us; speedup vs baseline: 1.1238x; 1.1091x over previous
//
#include <hip/hip_runtime.h>
#include <math.h>

#define N 1024
#define H 128
#define CLIPV 10.0f

#define TI 64
#define TJ 64
#define LDSP 132           // padded row stride: 132 % 32 = 4 -> 4-bank rotation/row
#define NBLK ((N / TI) * (N / TJ))   // 256 pair-blocks

// ---------------------------------------------------------------------------
// Kernel A: A[j][h]  = z_c @ w1[:128]           (j-side operand)
//           Cb[i][h] = z_d @ w1[128:] + b1      (i-side operand, bias folded)
// grid (N/8, 2), block 256. 8 rows/block staged in LDS.
// ---------------------------------------------------------------------------
__global__ __launch_bounds__(256) void k_gemm(const float* __restrict__ z_c,
                                              const float* __restrict__ z_d,
                                              const float* __restrict__ w1,
                                              const float* __restrict__ b1,
                                              float* __restrict__ A,
                                              float* __restrict__ Cb) {
    const int which = blockIdx.y;            // 0 -> A, 1 -> Cb
    const int n0 = blockIdx.x * 8;
    const int tid = threadIdx.x;
    const float* __restrict__ z = which ? z_d : z_c;
    const float* __restrict__ w = w1 + which * (H * H);

    __shared__ float zs[8][H];
    {
        const int c4 = (tid & 31) * 4;
        const int r  = tid >> 5;             // 0..7
        *(float4*)&zs[r][c4] = *(const float4*)&z[(n0 + r) * H + c4];
    }
    __syncthreads();

    const int h = tid & 127;
    const int g = tid >> 7;                  // row-group 0/1 (rows g*4..g*4+3)

    float a0 = 0.f, a1 = 0.f, a2 = 0.f, a3 = 0.f;
    #pragma unroll 8
    for (int k = 0; k < H; ++k) {
        const float wv = w[k * H + h];
        a0 = fmaf(zs[g * 4 + 0][k], wv, a0);
        a1 = fmaf(zs[g * 4 + 1][k], wv, a1);
        a2 = fmaf(zs[g * 4 + 2][k], wv, a2);
        a3 = fmaf(zs[g * 4 + 3][k], wv, a3);
    }
    const float bias = which ? b1[h] : 0.0f;
    float* __restrict__ dst = which ? Cb : A;
    dst[(n0 + g * 4 + 0) * H + h] = a0 + bias;
    dst[(n0 + g * 4 + 1) * H + h] = a1 + bias;
    dst[(n0 + g * 4 + 2) * H + h] = a2 + bias;
    dst[(n0 + g * 4 + 3) * H + h] = a3 + bias;
}

// ---------------------------------------------------------------------------
// Kernel B: pairwise T1 = sum_h relu(A[j][h]+Cb[i][h])*w2[h] + b2
// 64x64 tile per block, 512 threads = 2 h-halves x 256 compute threads.
// (512,1): uncapped VGPR — the allocator's deep unroll-4 ILP window carries
// this kernel; the (512,4)=128-VGPR cap was a -11% regression (R5/R8), and
// the atomic+fence merged-finalize was a -11% regression (R9). Proven 82.8.
// Per-block partials to arrays — no atomics, no fence.
// ---------------------------------------------------------------------------
__global__ __launch_bounds__(512, 1) void k_pair(const float* __restrict__ A,
                                                 const float* __restrict__ Cb,
                                                 const float* __restrict__ w2,
                                                 const float* __restrict__ b2p,
                                                 float* __restrict__ pdiag,
                                                 float* __restrict__ psume) {
    __shared__ float Ash[TJ][LDSP];
    __shared__ float Csh[TI][LDSP];
    __shared__ float w2s[H];
    __shared__ float red[16];

    const int tid = threadIdx.x;
    const int i0 = blockIdx.x * TI;
    const int j0 = blockIdx.y * TJ;

    // ---- staging: 512 threads, 128 rows (64 A + 64 C) x 32 float4 cols ----
    {
        const int c4 = (tid & 31) * 4;
        const int r  = tid >> 5;             // 0..15
        #pragma unroll
        for (int rr = 0; rr < 4; ++rr) {
            const int row = r + rr * 16;     // 0..63
            *(float4*)&Ash[row][c4] = *(const float4*)&A[(j0 + row) * H + c4];
            *(float4*)&Csh[row][c4] = *(const float4*)&Cb[(i0 + row) * H + c4];
        }
        if (tid < 32) *(float4*)&w2s[tid * 4] = *(const float4*)&w2[tid * 4];
    }
    __syncthreads();

    const int t256 = tid & 255;
    const int tj = t256 & 15;                // j group (16)
    const int ti = t256 >> 4;                // i group (16)
    const int hh = tid >> 8;                 // h-half 0/1

    float s[4][4] = {{0.f,0.f,0.f,0.f},{0.f,0.f,0.f,0.f},
                     {0.f,0.f,0.f,0.f},{0.f,0.f,0.f,0.f}};

    const int h4base = hh * 16;
    #pragma unroll 4
    for (int h4i = 0; h4i < 16; ++h4i) {
        const int h4 = h4base + h4i;
        const float4 w4 = *(const float4*)&w2s[h4 * 4];
        float4 cf[4], af[4];
        #pragma unroll
        for (int d = 0; d < 4; ++d) {
            cf[d] = *(const float4*)&Csh[ti + d * 16][h4 * 4];
            af[d] = *(const float4*)&Ash[tj + d * 16][h4 * 4];
        }
        #pragma unroll
        for (int q = 0; q < 4; ++q) {
            const float wv = ((const float*)&w4)[q];
            #pragma unroll
            for (int di = 0; di < 4; ++di) {
                const float cv = ((const float*)&cf[di])[q];
                #pragma unroll
                for (int dj = 0; dj < 4; ++dj) {
                    const float t = fmaxf(cv + ((const float*)&af[dj])[q], 0.f);
                    s[di][dj] = fmaf(t, wv, s[di][dj]);
                }
            }
        }
    }

    // ---- combine h-halves (reuse Ash as scratch; stride 20 -> <=2-way) ----
    float* comb = &Ash[0][0];                // 256*20 = 5120 <= 64*132
    __syncthreads();
    if (hh == 1) {
        #pragma unroll
        for (int di = 0; di < 4; ++di) {
            float4 v4;
            v4.x = s[di][0]; v4.y = s[di][1]; v4.z = s[di][2]; v4.w = s[di][3];
            *(float4*)&comb[t256 * 20 + di * 4] = v4;
        }
    }
    __syncthreads();

    float diag = 0.f, sume = 0.f;
    if (hh == 0) {
        const float b2 = b2p[0];
        #pragma unroll
        for (int di = 0; di < 4; ++di) {
            #pragma unroll
            for (int dj = 0; dj < 4; ++dj) {
                const float v = s[di][dj] + comb[t256 * 20 + di * 4 + dj] + b2;
                const int i = i0 + ti + di * 16;
                const int j = j0 + tj + dj * 16;
                if (i == j) {
                    diag += v;
                } else {
                    const float vc = fminf(fmaxf(v, -CLIPV), CLIPV);
                    sume += __expf(vc - CLIPV);
                }
            }
        }
    }

    // ---- block reduction: wave shuffle, then LDS across 8 waves ----
    #pragma unroll
    for (int off = 32; off; off >>= 1) {
        diag += __shfl_down(diag, off);
        sume += __shfl_down(sume, off);
    }
    if ((tid & 63) == 0) { red[tid >> 6] = diag; red[8 + (tid >> 6)] = sume; }
    __syncthreads();
    if (tid == 0) {
        float d = 0.f, e = 0.f;
        #pragma unroll
        for (int k = 0; k < 8; ++k) { d += red[k]; e += red[8 + k]; }
        const int bid = blockIdx.y * gridDim.x + blockIdx.x;
        pdiag[bid] = d;
        psume[bid] = e;
    }
}

// ---------------------------------------------------------------------------
// Kernel C: reduce 256 block-partials (f64) and finalize scalar
// ---------------------------------------------------------------------------
__global__ __launch_bounds__(256) void k_final(const float* __restrict__ pdiag,
                                               const float* __restrict__ psume,
                                               float* __restrict__ out) {
    const int tid = threadIdx.x;
    double d = (double)pdiag[tid];
    double e = (double)psume[tid];
    #pragma unroll
    for (int off = 32; off; off >>= 1) {
        d += __shfl_down(d, off);
        e += __shfl_down(e, off);
    }
    __shared__ double rd[4], re[4];
    if ((tid & 63) == 0) { rd[tid >> 6] = d; re[tid >> 6] = e; }
    __syncthreads();
    if (tid == 0) {
        const double dt = rd[0] + rd[1] + rd[2] + rd[3];
        const double et = re[0] + re[1] + re[2] + re[3];
        const double T0  = dt / (double)N;
        const double lme = log(et) + (double)CLIPV
                         - log((double)N * ((double)N - 1.0));
        out[0] = (float)(T0 - lme);
    }
}

extern "C" void kernel_launch(void* const* d_in, const int* in_sizes, int n_in,
                              void* d_out, int out_size, void* d_ws, size_t ws_size,
                              hipStream_t stream) {
    const float* z_c = (const float*)d_in[0];
    const float* z_d = (const float*)d_in[1];
    const float* w1  = (const float*)d_in[2];
    const float* b1  = (const float*)d_in[3];
    const float* w2  = (const float*)d_in[4];
    const float* b2  = (const float*)d_in[5];

    float* A     = (float*)d_ws;             // N*H
    float* Cb    = A + N * H;                // N*H
    float* pdiag = Cb + N * H;               // NBLK
    float* psume = pdiag + NBLK;             // NBLK

    k_gemm<<<dim3(N / 8, 2), 256, 0, stream>>>(z_c, z_d, w1, b1, A, Cb);
    k_pair<<<dim3(N / TI, N / TJ), 512, 0, stream>>>(A, Cb, w2, b2, pdiag, psume);
    k_final<<<1, 256, 0, stream>>>(pdiag, psume, (float*)d_out);
}